// Round 1
// baseline (1313.600 us; speedup 1.0000x reference)
//
#include <hip/hip_runtime.h>
#include <math.h>

// MRA attention, B=4 S=4096 H=768, 12 heads x 64, BLOCK=32, nb=128, top-512 blocks,
// FIRST_N=0 DIAG_N=3.  Selection path in f64 (matches numpy ref ordering), output path f32.

#define S_LEN 4096
#define NBLK  128
#define BHT   48
#define HD    64

// ---------------------------------------------------------------------------
// 1) QKV projection: fp32 tiled GEMM  C = X @ W^T + b, epilogue applies mask and
//    writes head-split layout  Out[bh][s][d],  bh = b*12 + h.
// ---------------------------------------------------------------------------
__global__ __launch_bounds__(256) void qkv_gemm(
    const float* __restrict__ X,
    const float* __restrict__ Wq, const float* __restrict__ Wk, const float* __restrict__ Wv,
    const float* __restrict__ bq, const float* __restrict__ bk, const float* __restrict__ bv,
    const float* __restrict__ am,
    float* __restrict__ Qo, float* __restrict__ Ko, float* __restrict__ Vo)
{
    const float* W; const float* bias; float* outp;
    if (blockIdx.z == 0)      { W = Wq; bias = bq; outp = Qo; }
    else if (blockIdx.z == 1) { W = Wk; bias = bk; outp = Ko; }
    else                      { W = Wv; bias = bv; outp = Vo; }
    const int m0 = blockIdx.y * 128, n0 = blockIdx.x * 128;
    __shared__ float As[16][132];
    __shared__ float Bs[16][132];
    const int tid = threadIdx.x;
    const int tx = tid & 15, ty = tid >> 4;
    float acc[8][8] = {};
    const int lr = tid >> 2, lc = (tid & 3) * 4;
    for (int k0 = 0; k0 < 768; k0 += 16) {
        float4 a0 = *(const float4*)&X[(size_t)(m0 + lr)      * 768 + k0 + lc];
        float4 a1 = *(const float4*)&X[(size_t)(m0 + lr + 64) * 768 + k0 + lc];
        float4 b0 = *(const float4*)&W[(size_t)(n0 + lr)      * 768 + k0 + lc];
        float4 b1 = *(const float4*)&W[(size_t)(n0 + lr + 64) * 768 + k0 + lc];
        __syncthreads();
        As[lc+0][lr]    = a0.x; As[lc+1][lr]    = a0.y; As[lc+2][lr]    = a0.z; As[lc+3][lr]    = a0.w;
        As[lc+0][lr+64] = a1.x; As[lc+1][lr+64] = a1.y; As[lc+2][lr+64] = a1.z; As[lc+3][lr+64] = a1.w;
        Bs[lc+0][lr]    = b0.x; Bs[lc+1][lr]    = b0.y; Bs[lc+2][lr]    = b0.z; Bs[lc+3][lr]    = b0.w;
        Bs[lc+0][lr+64] = b1.x; Bs[lc+1][lr+64] = b1.y; Bs[lc+2][lr+64] = b1.z; Bs[lc+3][lr+64] = b1.w;
        __syncthreads();
        #pragma unroll
        for (int kk = 0; kk < 16; ++kk) {
            float af[8], bf[8];
            *(float4*)&af[0] = *(const float4*)&As[kk][ty*8];
            *(float4*)&af[4] = *(const float4*)&As[kk][ty*8+4];
            *(float4*)&bf[0] = *(const float4*)&Bs[kk][tx*8];
            *(float4*)&bf[4] = *(const float4*)&Bs[kk][tx*8+4];
            #pragma unroll
            for (int i = 0; i < 8; ++i)
                #pragma unroll
                for (int j = 0; j < 8; ++j)
                    acc[i][j] += af[i] * bf[j];
        }
    }
    #pragma unroll
    for (int i = 0; i < 8; ++i) {
        int t = m0 + ty*8 + i;
        int b = t >> 12, s = t & 4095;
        float mv = 1.0f + am[t] * 1e-4f;
        #pragma unroll
        for (int j = 0; j < 8; ++j) {
            int o = n0 + tx*8 + j;
            int h = o >> 6, d = o & 63;
            outp[(((size_t)(b*12 + h)) * S_LEN + s) * HD + d] = (acc[i][j] + bias[o]) * mv;
        }
    }
}

// ---------------------------------------------------------------------------
// 2) f64 selection path: mask-weighted block sums of hidden states.
//    hsum[b*128+blk][768], tcd[b*128+blk]
// ---------------------------------------------------------------------------
__global__ __launch_bounds__(256) void hsum_kernel(
    const float* __restrict__ X, const float* __restrict__ am,
    double* __restrict__ hsum, double* __restrict__ tcd)
{
    int blk = blockIdx.x & 127, b = blockIdx.x >> 7;
    int tid = threadIdx.x;
    const float* xb  = X  + ((size_t)(b * S_LEN + blk * 32)) * 768;
    const float* amb = am + b * S_LEN + blk * 32;
    for (int d = tid; d < 768; d += 256) {
        double s = 0.0;
        for (int t = 0; t < 32; ++t)
            s += (double)xb[(size_t)t * 768 + d] * (1.0 + (double)amb[t] * 1e-4);
        hsum[(size_t)blockIdx.x * 768 + d] = s;
    }
    if (tid == 0) {
        double t = 0.0;
        for (int i = 0; i < 32; ++i) t += 1.0 + (double)amb[i] * 1e-4;
        tcd[blockIdx.x] = t;
    }
}

// ---------------------------------------------------------------------------
// 3) qhat/khat (f64):  qhat = (hsum @ W^T + tc*b) / (tc + 1e-6), head-split layout
//    [bh][blk][64].  64x64 tile, f64 accumulation, f32 weights.
// ---------------------------------------------------------------------------
__global__ __launch_bounds__(256) void ghat_kernel(
    const double* __restrict__ hsum,
    const float* __restrict__ Wq, const float* __restrict__ Wk,
    const float* __restrict__ bq, const float* __restrict__ bk,
    const double* __restrict__ tcd,
    double* __restrict__ qhat, double* __restrict__ khat)
{
    const float* W; const float* bias; double* outp;
    if (blockIdx.z == 0) { W = Wq; bias = bq; outp = qhat; }
    else                 { W = Wk; bias = bk; outp = khat; }
    const int n0 = blockIdx.x * 64, m0 = blockIdx.y * 64;
    __shared__ double As[16][72];
    __shared__ float  Bs[16][72];
    const int tid = threadIdx.x;
    const int tx = tid & 15, ty = tid >> 4;
    double acc[4][4] = {};
    const int lr = tid >> 2, lc = (tid & 3) * 4;
    for (int k0 = 0; k0 < 768; k0 += 16) {
        double a0 = hsum[(size_t)(m0 + lr) * 768 + k0 + lc + 0];
        double a1 = hsum[(size_t)(m0 + lr) * 768 + k0 + lc + 1];
        double a2 = hsum[(size_t)(m0 + lr) * 768 + k0 + lc + 2];
        double a3 = hsum[(size_t)(m0 + lr) * 768 + k0 + lc + 3];
        float4 bv = *(const float4*)&W[(size_t)(n0 + lr) * 768 + k0 + lc];
        __syncthreads();
        As[lc+0][lr] = a0; As[lc+1][lr] = a1; As[lc+2][lr] = a2; As[lc+3][lr] = a3;
        Bs[lc+0][lr] = bv.x; Bs[lc+1][lr] = bv.y; Bs[lc+2][lr] = bv.z; Bs[lc+3][lr] = bv.w;
        __syncthreads();
        #pragma unroll
        for (int kk = 0; kk < 16; ++kk) {
            double af[4]; float bf[4];
            #pragma unroll
            for (int i = 0; i < 4; ++i) af[i] = As[kk][ty*4+i];
            #pragma unroll
            for (int j = 0; j < 4; ++j) bf[j] = Bs[kk][tx*4+j];
            #pragma unroll
            for (int i = 0; i < 4; ++i)
                #pragma unroll
                for (int j = 0; j < 4; ++j)
                    acc[i][j] += af[i] * (double)bf[j];
        }
    }
    #pragma unroll
    for (int i = 0; i < 4; ++i) {
        int m = m0 + ty*4 + i;
        int b = m >> 7, blk = m & 127;
        double t = tcd[m];
        #pragma unroll
        for (int j = 0; j < 4; ++j) {
            int o = n0 + tx*4 + j;
            int h = o >> 6, d = o & 63;
            outp[(((size_t)(b*12 + h)) * NBLK + blk) * HD + d] = (acc[i][j] + t * (double)bias[o]) / (t + 1e-6);
        }
    }
}

// ---------------------------------------------------------------------------
// 4) low-res logits (f64): lrl[bh][qi][ki] = qhat.khat/8 (- 1e4 if tc*tc<0.5),
//    rowmax from raw values.
// ---------------------------------------------------------------------------
__global__ __launch_bounds__(128) void lrl_kernel(
    const double* __restrict__ qhat, const double* __restrict__ khat,
    const double* __restrict__ tcd,
    double* __restrict__ lrl, double* __restrict__ rmax)
{
    const int qi = blockIdx.x, bh = blockIdx.y;
    const int b = bh / 12;
    __shared__ double qr[64];
    __shared__ double red[128];
    const int tid = threadIdx.x;
    if (tid < 64) qr[tid] = qhat[(((size_t)bh) * NBLK + qi) * HD + tid];
    __syncthreads();
    const double* kr = &khat[(((size_t)bh) * NBLK + tid) * HD];
    double s = 0.0;
    for (int d = 0; d < 64; ++d) s += qr[d] * kr[d];
    s *= 0.125;
    red[tid] = s;
    __syncthreads();
    for (int off = 64; off > 0; off >>= 1) {
        if (tid < off) red[tid] = fmax(red[tid], red[tid + off]);
        __syncthreads();
    }
    double pen = (tcd[b * NBLK + qi] * tcd[b * NBLK + tid] < 0.5) ? 1e4 : 0.0;
    lrl[(size_t)bh * (NBLK*NBLK) + (size_t)qi * NBLK + tid] = s - pen;
    if (tid == 0) rmax[bh * NBLK + qi] = red[0];
}

// ---------------------------------------------------------------------------
// 5) v_hat (f32) + tc (f32)
// ---------------------------------------------------------------------------
__global__ __launch_bounds__(64) void vhat_kernel(
    const float* __restrict__ V, const float* __restrict__ am,
    float* __restrict__ vhat, float* __restrict__ tcf)
{
    int blk = blockIdx.x & 127, bh = blockIdx.x >> 7;
    int b = bh / 12;
    int d = threadIdx.x;
    const float* amb = am + b * S_LEN + blk * 32;
    float tc = 0.f;
    for (int t = 0; t < 32; ++t) tc += 1.0f + amb[t] * 1e-4f;
    float s = 0.f;
    size_t base = (((size_t)bh) * S_LEN + blk * 32) * HD + d;
    for (int t = 0; t < 32; ++t) s += V[base + (size_t)t * HD];
    vhat[(((size_t)bh) * NBLK + blk) * HD + d] = s / (tc + 1e-6f);
    if (d == 0) tcf[bh * NBLK + blk] = tc;
}

// ---------------------------------------------------------------------------
// 6) top-512 radix select (u64 sortable keys, f64 values) + per-(bh,qi) lists.
//    Tie semantics match jax.lax.top_k: smallest flat index first.
// ---------------------------------------------------------------------------
__device__ __forceinline__ unsigned long long sel_key(const double* lp, const double* rm, int i)
{
    int qi = i >> 7, ki = i & 127;
    double s = lp[i] - rm[qi];
    int dd = qi - ki; if (dd < 0) dd = -dd;
    if (dd <= 1) s += 5000.0;
    unsigned long long u = (unsigned long long)__double_as_longlong(s);
    u = (u >> 63) ? ~u : (u | 0x8000000000000000ULL);
    return u;
}

__global__ __launch_bounds__(256) void topk_kernel(
    const double* __restrict__ lrl, const double* __restrict__ rmax,
    double* __restrict__ th64, int* __restrict__ cnt, unsigned char* __restrict__ lists,
    int* __restrict__ eqbuf, int* __restrict__ eqcnt)
{
    const int bh = blockIdx.x, tid = threadIdx.x;
    __shared__ int hist[256];
    __shared__ unsigned long long s_pref;
    __shared__ int s_K;
    const double* lp = lrl + (size_t)bh * (NBLK*NBLK);
    const double* rm = rmax + bh * NBLK;
    if (tid < 128) cnt[bh * NBLK + tid] = 0;
    if (tid == 0) eqcnt[bh] = 0;

    unsigned long long pref = 0, pmask = 0;
    int K = 512;
    for (int by = 7; by >= 0; --by) {
        hist[tid] = 0;
        __syncthreads();
        for (int i = tid; i < NBLK*NBLK; i += 256) {
            unsigned long long u = sel_key(lp, rm, i);
            if ((u & pmask) == pref)
                atomicAdd(&hist[(int)((u >> (by*8)) & 255)], 1);
        }
        __syncthreads();
        if (tid == 0) {
            int c = 0, bsel = 0;
            for (int x = 255; x >= 0; --x) {
                if (c + hist[x] >= K) { bsel = x; break; }
                c += hist[x];
            }
            s_pref = pref | ((unsigned long long)bsel << (by*8));
            s_K = K - c;
        }
        __syncthreads();
        pref = s_pref; K = s_K;
        pmask |= 0xFFULL << (by*8);
        __syncthreads();
    }
    const unsigned long long tkey = pref;
    int n_take = K;
    if (tid == 0) {
        unsigned long long u = (tkey & 0x8000000000000000ULL) ? (tkey ^ 0x8000000000000000ULL) : ~tkey;
        th64[bh] = __longlong_as_double((long long)u);
    }
    // fill per-row lists
    for (int i = tid; i < NBLK*NBLK; i += 256) {
        unsigned long long u = sel_key(lp, rm, i);
        if (u > tkey) {
            int qi = i >> 7, ki = i & 127;
            int pos = atomicAdd(&cnt[bh * NBLK + qi], 1);
            lists[(((size_t)bh) * NBLK + qi) * NBLK + pos] = (unsigned char)ki;
        } else if (u == tkey) {
            int e = atomicAdd(&eqcnt[bh], 1);
            if (e < 512) eqbuf[bh * 512 + e] = i;
        }
    }
    __syncthreads();
    if (tid == 0) {
        int ne = eqcnt[bh]; if (ne > 512) ne = 512;
        int* eb = &eqbuf[bh * 512];
        for (int a = 1; a < ne; ++a) {       // ascending flat index
            int v = eb[a]; int x = a - 1;
            while (x >= 0 && eb[x] > v) { eb[x+1] = eb[x]; --x; }
            eb[x+1] = v;
        }
        if (n_take > ne) n_take = ne;
        for (int j = 0; j < n_take; ++j) {
            int i = eb[j]; int qi = i >> 7, ki = i & 127;
            int pos = cnt[bh * NBLK + qi]++;
            lists[(((size_t)bh) * NBLK + qi) * NBLK + pos] = (unsigned char)ki;
        }
    }
    __syncthreads();
    // sort each row's list -> deterministic accumulation order + better locality
    if (tid < 128) {
        int n = cnt[bh * NBLK + tid];
        unsigned char* l = &lists[(((size_t)bh) * NBLK + tid) * NBLK];
        for (int a = 1; a < n; ++a) {
            unsigned char v = l[a]; int x = a - 1;
            while (x >= 0 && l[x] > v) { l[x+1] = l[x]; --x; }
            l[x+1] = v;
        }
    }
}

// ---------------------------------------------------------------------------
// 7) High-res sparse attention + low-res branch + combine.
//    One workgroup per (bh, query block). 256 threads.
// ---------------------------------------------------------------------------
__device__ __forceinline__ float dot64(const float (*kv)[68], int k, const float* qreg)
{
    float s = 0.f;
    #pragma unroll
    for (int x = 0; x < 16; ++x) {
        float4 kvv = *(const float4*)&kv[k][x*4];
        s += kvv.x * qreg[x*4+0];
        s += kvv.y * qreg[x*4+1];
        s += kvv.z * qreg[x*4+2];
        s += kvv.w * qreg[x*4+3];
    }
    return s;
}

__global__ __launch_bounds__(256) void hr_kernel(
    const float* __restrict__ Q, const float* __restrict__ Kf, const float* __restrict__ Vf,
    const double* __restrict__ lrl64, const double* __restrict__ rmax64, const double* __restrict__ th64,
    const int* __restrict__ cnt, const unsigned char* __restrict__ lists,
    const float* __restrict__ vhat, const float* __restrict__ tcf,
    const float* __restrict__ am, float* __restrict__ out)
{
    const int qi = blockIdx.x, bh = blockIdx.y;
    const int tid = threadIdx.x;
    __shared__ float qb[32][68];
    __shared__ float kv[32][68];
    __shared__ float vb[32][68];
    __shared__ float eL[32][33];
    __shared__ float red[8][33];
    __shared__ float mrow[32], nrm[32], wlr[128], lrvec[64];
    __shared__ float s_lrn;

    const int q  = tid & 31;
    const int g  = tid >> 5;     // 0..7
    const int d0 = g * 8;

    // stage Q block -> LDS
    {
        int t = tid >> 3, dq = (tid & 7) * 8;
        const float* src = &Q[(((size_t)bh) * S_LEN + qi*32 + t) * HD + dq];
        float4 x0 = *(const float4*)src, x1 = *(const float4*)(src + 4);
        qb[t][dq+0]=x0.x; qb[t][dq+1]=x0.y; qb[t][dq+2]=x0.z; qb[t][dq+3]=x0.w;
        qb[t][dq+4]=x1.x; qb[t][dq+5]=x1.y; qb[t][dq+6]=x1.z; qb[t][dq+7]=x1.w;
    }
    if (tid < 32) mrow[tid] = -1e9f;
    const int c = cnt[bh * NBLK + qi];
    const unsigned char* ml = &lists[(((size_t)bh) * NBLK + qi) * NBLK];
    __syncthreads();

    // own Q row in registers
    float qreg[64];
    #pragma unroll
    for (int x = 0; x < 16; ++x) {
        float4 t4 = *(const float4*)&qb[q][x*4];
        qreg[x*4+0]=t4.x; qreg[x*4+1]=t4.y; qreg[x*4+2]=t4.z; qreg[x*4+3]=t4.w;
    }

    // ---- pass 1: per-query-row max over selected blocks ----
    for (int bi = 0; bi < c; ++bi) {
        int ki = ml[bi];
        int t = tid >> 3, dq = (tid & 7) * 8;
        const float* ks = &Kf[(((size_t)bh) * S_LEN + ki*32 + t) * HD + dq];
        float4 k0 = *(const float4*)ks, k1 = *(const float4*)(ks + 4);
        __syncthreads();
        kv[t][dq+0]=k0.x; kv[t][dq+1]=k0.y; kv[t][dq+2]=k0.z; kv[t][dq+3]=k0.w;
        kv[t][dq+4]=k1.x; kv[t][dq+5]=k1.y; kv[t][dq+6]=k1.z; kv[t][dq+7]=k1.w;
        __syncthreads();
        float lm = -1e30f;
        #pragma unroll
        for (int j = 0; j < 4; ++j) {
            float s = dot64(kv, g*4 + j, qreg) * 0.125f;
            lm = fmaxf(lm, s);
        }
        red[g][q] = lm;
        __syncthreads();
        if (tid < 32) {
            float m = mrow[tid];
            #pragma unroll
            for (int x = 0; x < 8; ++x) m = fmaxf(m, red[x][tid]);
            mrow[tid] = m;
        }
    }
    __syncthreads();

    // ---- pass 2: exp + accumulate PV ----
    float acc[8] = {0,0,0,0,0,0,0,0};
    float nsum = 0.f;
    for (int bi = 0; bi < c; ++bi) {
        int ki = ml[bi];
        int t = tid >> 3, dq = (tid & 7) * 8;
        const float* ks = &Kf[(((size_t)bh) * S_LEN + ki*32 + t) * HD + dq];
        const float* vs = &Vf[(((size_t)bh) * S_LEN + ki*32 + t) * HD + dq];
        float4 k0 = *(const float4*)ks, k1 = *(const float4*)(ks + 4);
        float4 v0 = *(const float4*)vs, v1 = *(const float4*)(vs + 4);
        __syncthreads();
        kv[t][dq+0]=k0.x; kv[t][dq+1]=k0.y; kv[t][dq+2]=k0.z; kv[t][dq+3]=k0.w;
        kv[t][dq+4]=k1.x; kv[t][dq+5]=k1.y; kv[t][dq+6]=k1.z; kv[t][dq+7]=k1.w;
        vb[t][dq+0]=v0.x; vb[t][dq+1]=v0.y; vb[t][dq+2]=v0.z; vb[t][dq+3]=v0.w;
        vb[t][dq+4]=v1.x; vb[t][dq+5]=v1.y; vb[t][dq+6]=v1.z; vb[t][dq+7]=v1.w;
        __syncthreads();
        #pragma unroll
        for (int j = 0; j < 4; ++j) {
            int k = g*4 + j;
            float s = dot64(kv, k, qreg) * 0.125f;
            eL[k][q] = expf(s - mrow[q]);
        }
        __syncthreads();
        #pragma unroll 4
        for (int k = 0; k < 32; ++k) {
            float e = eL[k][q];
            if (g == 0) nsum += e;
            float4 w0 = *(const float4*)&vb[k][d0];
            float4 w1 = *(const float4*)&vb[k][d0+4];
            acc[0] += e*w0.x; acc[1] += e*w0.y; acc[2] += e*w0.z; acc[3] += e*w0.w;
            acc[4] += e*w1.x; acc[5] += e*w1.y; acc[6] += e*w1.z; acc[7] += e*w1.w;
        }
    }
    if (g == 0) nrm[q] = nsum;
    __syncthreads();

    // ---- low-res branch for this query block ----
    const double thv  = th64[bh];
    const double rm64 = rmax64[bh * NBLK + qi];
    if (tid < 128) {
        int m = tid;
        double lv = lrl64[(size_t)bh * (NBLK*NBLK) + (size_t)qi * NBLK + m];
        int dd = qi - m; if (dd < 0) dd = -dd;
        double s = lv - rm64 + ((dd <= 1) ? 5000.0 : 0.0);
        float w;
        if (s >= thv) w = 0.f;                          // hi block: exp(x-1e4) == 0
        else          w = (float)exp(lv - rm64) * tcf[bh * NBLK + m];
        wlr[m] = w;
    }
    __syncthreads();
    if (tid == 0) {
        float t = 0.f;
        for (int m = 0; m < 128; ++m) t += wlr[m];
        s_lrn = t;
    }
    if (tid < 64) {
        float a = 0.f;
        for (int m = 0; m < 128; ++m)
            a += wlr[m] * vhat[(((size_t)bh) * NBLK + m) * HD + tid];
        lrvec[tid] = a;
    }
    __syncthreads();

    // ---- combine & write ----
    const int b = bh / 12, h = bh % 12;
    const int srow = qi*32 + q;
    float mv  = 1.0f + am[b * S_LEN + srow] * 1e-4f;
    float mq  = mrow[q];
    float logc = ((float)rm64 - mq) * mv;
    float lrc = (logc <= 0.f) ? expf(logc)  : 1.0f;
    float hrc = (logc >  0.f) ? expf(-logc) : 1.0f;
    float den = nrm[q] * hrc + s_lrn * lrc + 1e-6f;
    float sc  = mv / den;
    size_t ob = ((size_t)(b * S_LEN + srow)) * 768 + h * HD + d0;
    #pragma unroll
    for (int j = 0; j < 8; ++j)
        out[ob + j] = (acc[j] * hrc + lrvec[d0 + j] * lrc) * sc;
}

// ---------------------------------------------------------------------------
extern "C" void kernel_launch(void* const* d_in, const int* in_sizes, int n_in,
                              void* d_out, int out_size, void* d_ws, size_t ws_size,
                              hipStream_t stream)
{
    (void)in_sizes; (void)n_in; (void)out_size; (void)ws_size;
    const float* X  = (const float*)d_in[0];
    const float* am = (const float*)d_in[1];
    const float* Wq = (const float*)d_in[2];
    const float* bq = (const float*)d_in[3];
    const float* Wk = (const float*)d_in[4];
    const float* bk = (const float*)d_in[5];
    const float* Wv = (const float*)d_in[6];
    const float* bv = (const float*)d_in[7];
    float* out = (float*)d_out;

    char* p = (char*)d_ws;
    double* hsum   = (double*)p; p += (size_t)512 * 768 * 8;
    double* tcd    = (double*)p; p += (size_t)512 * 8;
    double* qhat64 = (double*)p; p += (size_t)BHT * NBLK * HD * 8;
    double* khat64 = (double*)p; p += (size_t)BHT * NBLK * HD * 8;
    double* lrl64  = (double*)p; p += (size_t)BHT * NBLK * NBLK * 8;
    double* rmax64 = (double*)p; p += (size_t)BHT * NBLK * 8;
    double* th64   = (double*)p; p += (size_t)BHT * 8;
    float* Qf   = (float*)p; p += (size_t)BHT * S_LEN * HD * 4;
    float* Kf   = (float*)p; p += (size_t)BHT * S_LEN * HD * 4;
    float* Vf   = (float*)p; p += (size_t)BHT * S_LEN * HD * 4;
    float* vhat = (float*)p; p += (size_t)BHT * NBLK * HD * 4;
    float* tcf  = (float*)p; p += (size_t)BHT * NBLK * 4;
    int* cnt    = (int*)p;   p += (size_t)BHT * NBLK * 4;
    int* eqbuf  = (int*)p;   p += (size_t)BHT * 512 * 4;
    int* eqcnt  = (int*)p;   p += (size_t)BHT * 4;
    unsigned char* lists = (unsigned char*)p; p += (size_t)BHT * NBLK * NBLK;

    qkv_gemm<<<dim3(6, 128, 3), 256, 0, stream>>>(X, Wq, Wk, Wv, bq, bk, bv, am, Qf, Kf, Vf);
    hsum_kernel<<<512, 256, 0, stream>>>(X, am, hsum, tcd);
    ghat_kernel<<<dim3(12, 8, 2), 256, 0, stream>>>(hsum, Wq, Wk, bq, bk, tcd, qhat64, khat64);
    lrl_kernel<<<dim3(128, BHT), 128, 0, stream>>>(qhat64, khat64, tcd, lrl64, rmax64);
    vhat_kernel<<<BHT * NBLK, 64, 0, stream>>>(Vf, am, vhat, tcf);
    topk_kernel<<<BHT, 256, 0, stream>>>(lrl64, rmax64, th64, cnt, lists, eqbuf, eqcnt);
    hr_kernel<<<dim3(NBLK, BHT), 256, 0, stream>>>(Qf, Kf, Vf, lrl64, rmax64, th64,
                                                   cnt, lists, vhat, tcf, am, out);
}

// Round 2
// 877.545 us; speedup vs baseline: 1.4969x; 1.4969x over previous
//
#include <hip/hip_runtime.h>
#include <math.h>

// MRA attention, B=4 S=4096 H=768, 12 heads x 64, BLOCK=32, nb=128, top-512 blocks.
// Selection path f64; QKV projection via split-bf16 MFMA (hi/lo, 3 products).

#define S_LEN 4096
#define NBLK  128
#define BHT   48
#define HD    64

typedef __attribute__((ext_vector_type(8))) short bf16x8;
typedef __attribute__((ext_vector_type(4))) float f32x4;
typedef unsigned short u16;
typedef unsigned int   u32;

__device__ __forceinline__ u16 bf16rne(float x) {
    u32 u = __float_as_uint(x);
    u32 r = u + 0x7FFFu + ((u >> 16) & 1u);
    return (u16)(r >> 16);
}

__device__ __forceinline__ void gload_lds16(const void* g, void* l) {
    __builtin_amdgcn_global_load_lds((const __attribute__((address_space(1))) void*)g,
                                     (__attribute__((address_space(3))) void*)l, 16, 0, 0);
}

// ---------------------------------------------------------------------------
// 0) split f32 -> bf16 hi/lo planes (RNE).  n8 = elements/8.
// ---------------------------------------------------------------------------
__global__ __launch_bounds__(256) void split_kernel(
    const float* __restrict__ x, u16* __restrict__ hi, u16* __restrict__ lo, int n8)
{
    int i = blockIdx.x * 256 + threadIdx.x;
    if (i >= n8) return;
    const float4* xp = (const float4*)x + (size_t)i * 2;
    float4 a = xp[0], b = xp[1];
    float xs[8] = {a.x, a.y, a.z, a.w, b.x, b.y, b.z, b.w};
    bf16x8 vh, vl;
    #pragma unroll
    for (int j = 0; j < 8; ++j) {
        u16 hh = bf16rne(xs[j]);
        float hf = __uint_as_float((u32)hh << 16);
        vh[j] = (short)hh;
        vl[j] = (short)bf16rne(xs[j] - hf);
    }
    *(bf16x8*)&hi[(size_t)i * 8] = vh;
    *(bf16x8*)&lo[(size_t)i * 8] = vl;
}

// ---------------------------------------------------------------------------
// 1) QKV projection: split-bf16 MFMA GEMM.  C = X@W^T + b, epilogue mask,
//    head-split output Out[bh][s][d].  128x128 tile, BK=32, 4 waves (2x2).
//    LDS staged in MFMA-fragment order via global_load_lds (16B/lane).
// ---------------------------------------------------------------------------
__global__ __launch_bounds__(256) void qkv_mfma(
    const u16* __restrict__ Xh, const u16* __restrict__ Xl,
    const u16* __restrict__ Wh, const u16* __restrict__ Wl,   // [3][768][768]
    const float* __restrict__ bq, const float* __restrict__ bk, const float* __restrict__ bv,
    const float* __restrict__ am,
    float* __restrict__ Qo, float* __restrict__ Ko, float* __restrict__ Vo)
{
    const int z = blockIdx.z;
    const float* bias = (z == 0) ? bq : (z == 1) ? bk : bv;
    float* outp       = (z == 0) ? Qo : (z == 1) ? Ko : Vo;
    const u16* Wzh = Wh + (size_t)z * 768 * 768;
    const u16* Wzl = Wl + (size_t)z * 768 * 768;
    const int m0 = blockIdx.y * 128, n0 = blockIdx.x * 128;

    __shared__ char smem[32768];     // Ah | Al | Bh | Bl, each 8 KiB (8 subtiles of 1 KiB)
    const int tid  = threadIdx.x;
    const int lane = tid & 63;
    const int w    = tid >> 6;                    // 4 waves
    const int wm   = (w >> 1) * 64, wn = (w & 1) * 64;

    // wave w stages one plane: 0=Ah 1=Al 2=Bh 3=Bl
    const u16* splane = (w == 0) ? Xh : (w == 1) ? Xl : (w == 2) ? Wzh : Wzl;
    const int rbase   = (w < 2) ? m0 : n0;
    const int ldsbase = w * 8192;
    const int srow = lane & 15, sk = (lane >> 4) * 8;   // fragment-order source coords

    f32x4 acc[4][4];
    #pragma unroll
    for (int i = 0; i < 4; ++i)
        #pragma unroll
        for (int j = 0; j < 4; ++j) acc[i][j] = (f32x4){0.f, 0.f, 0.f, 0.f};

    for (int k0 = 0; k0 < 768; k0 += 32) {
        __syncthreads();                 // previous iteration's ds_reads done
        #pragma unroll
        for (int i = 0; i < 8; ++i) {
            const u16* g = splane + (size_t)(rbase + i * 16 + srow) * 768 + (k0 + sk);
            gload_lds16(g, &smem[ldsbase + i * 1024]);
        }
        __syncthreads();                 // vmcnt(0) drained by compiler before barrier

        bf16x8 afh[4], afl[4], bfh[4], bfl[4];
        #pragma unroll
        for (int f = 0; f < 4; ++f) {
            int sa = (w >> 1) * 4 + f;
            int sb = (w & 1) * 4 + f;
            afh[f] = *(const bf16x8*)&smem[0     + sa * 1024 + lane * 16];
            afl[f] = *(const bf16x8*)&smem[8192  + sa * 1024 + lane * 16];
            bfh[f] = *(const bf16x8*)&smem[16384 + sb * 1024 + lane * 16];
            bfl[f] = *(const bf16x8*)&smem[24576 + sb * 1024 + lane * 16];
        }
        #pragma unroll
        for (int i = 0; i < 4; ++i)
            #pragma unroll
            for (int j = 0; j < 4; ++j) {
                acc[i][j] = __builtin_amdgcn_mfma_f32_16x16x32_bf16(afh[i], bfh[j], acc[i][j], 0, 0, 0);
                acc[i][j] = __builtin_amdgcn_mfma_f32_16x16x32_bf16(afh[i], bfl[j], acc[i][j], 0, 0, 0);
                acc[i][j] = __builtin_amdgcn_mfma_f32_16x16x32_bf16(afl[i], bfh[j], acc[i][j], 0, 0, 0);
            }
    }

    // epilogue: C/D layout col=lane&15, row=(lane>>4)*4+reg  [m89-verified]
    #pragma unroll
    for (int i = 0; i < 4; ++i) {
        #pragma unroll
        for (int j = 0; j < 4; ++j) {
            int col = n0 + wn + j * 16 + (lane & 15);       // output feature
            int h = col >> 6, d = col & 63;
            float bsv = bias[col];
            #pragma unroll
            for (int r = 0; r < 4; ++r) {
                int row = m0 + wm + i * 16 + (lane >> 4) * 4 + r;   // token
                int b = row >> 12, s = row & 4095;
                float mv = 1.0f + am[row] * 1e-4f;
                outp[(((size_t)(b * 12 + h)) * S_LEN + s) * HD + d] = (acc[i][j][r] + bsv) * mv;
            }
        }
    }
}

// ---------------------------------------------------------------------------
// 2) f64 selection path: mask-weighted block sums of hidden states.
// ---------------------------------------------------------------------------
__global__ __launch_bounds__(256) void hsum_kernel(
    const float* __restrict__ X, const float* __restrict__ am,
    double* __restrict__ hsum, double* __restrict__ tcd)
{
    int blk = blockIdx.x & 127, b = blockIdx.x >> 7;
    int tid = threadIdx.x;
    const float* xb  = X  + ((size_t)(b * S_LEN + blk * 32)) * 768;
    const float* amb = am + b * S_LEN + blk * 32;
    for (int d = tid; d < 768; d += 256) {
        double s = 0.0;
        for (int t = 0; t < 32; ++t)
            s += (double)xb[(size_t)t * 768 + d] * (1.0 + (double)amb[t] * 1e-4);
        hsum[(size_t)blockIdx.x * 768 + d] = s;
    }
    if (tid == 0) {
        double t = 0.0;
        for (int i = 0; i < 32; ++i) t += 1.0 + (double)amb[i] * 1e-4;
        tcd[blockIdx.x] = t;
    }
}

// ---------------------------------------------------------------------------
// 3) qhat/khat (f64)
// ---------------------------------------------------------------------------
__global__ __launch_bounds__(256) void ghat_kernel(
    const double* __restrict__ hsum,
    const float* __restrict__ Wq, const float* __restrict__ Wk,
    const float* __restrict__ bq, const float* __restrict__ bk,
    const double* __restrict__ tcd,
    double* __restrict__ qhat, double* __restrict__ khat)
{
    const float* W; const float* bias; double* outp;
    if (blockIdx.z == 0) { W = Wq; bias = bq; outp = qhat; }
    else                 { W = Wk; bias = bk; outp = khat; }
    const int n0 = blockIdx.x * 64, m0 = blockIdx.y * 64;
    __shared__ double As[16][72];
    __shared__ float  Bs[16][72];
    const int tid = threadIdx.x;
    const int tx = tid & 15, ty = tid >> 4;
    double acc[4][4] = {};
    const int lr = tid >> 2, lc = (tid & 3) * 4;
    for (int k0 = 0; k0 < 768; k0 += 16) {
        double a0 = hsum[(size_t)(m0 + lr) * 768 + k0 + lc + 0];
        double a1 = hsum[(size_t)(m0 + lr) * 768 + k0 + lc + 1];
        double a2 = hsum[(size_t)(m0 + lr) * 768 + k0 + lc + 2];
        double a3 = hsum[(size_t)(m0 + lr) * 768 + k0 + lc + 3];
        float4 bv = *(const float4*)&W[(size_t)(n0 + lr) * 768 + k0 + lc];
        __syncthreads();
        As[lc+0][lr] = a0; As[lc+1][lr] = a1; As[lc+2][lr] = a2; As[lc+3][lr] = a3;
        Bs[lc+0][lr] = bv.x; Bs[lc+1][lr] = bv.y; Bs[lc+2][lr] = bv.z; Bs[lc+3][lr] = bv.w;
        __syncthreads();
        #pragma unroll
        for (int kk = 0; kk < 16; ++kk) {
            double af[4]; float bf[4];
            #pragma unroll
            for (int i = 0; i < 4; ++i) af[i] = As[kk][ty*4+i];
            #pragma unroll
            for (int j = 0; j < 4; ++j) bf[j] = Bs[kk][tx*4+j];
            #pragma unroll
            for (int i = 0; i < 4; ++i)
                #pragma unroll
                for (int j = 0; j < 4; ++j)
                    acc[i][j] += af[i] * (double)bf[j];
        }
    }
    #pragma unroll
    for (int i = 0; i < 4; ++i) {
        int m = m0 + ty*4 + i;
        int b = m >> 7, blk = m & 127;
        double t = tcd[m];
        #pragma unroll
        for (int j = 0; j < 4; ++j) {
            int o = n0 + tx*4 + j;
            int h = o >> 6, d = o & 63;
            outp[(((size_t)(b*12 + h)) * NBLK + blk) * HD + d] = (acc[i][j] + t * (double)bias[o]) / (t + 1e-6);
        }
    }
}

// ---------------------------------------------------------------------------
// 4) low-res logits (f64)
// ---------------------------------------------------------------------------
__global__ __launch_bounds__(128) void lrl_kernel(
    const double* __restrict__ qhat, const double* __restrict__ khat,
    const double* __restrict__ tcd,
    double* __restrict__ lrl, double* __restrict__ rmax)
{
    const int qi = blockIdx.x, bh = blockIdx.y;
    const int b = bh / 12;
    __shared__ double qr[64];
    __shared__ double red[128];
    const int tid = threadIdx.x;
    if (tid < 64) qr[tid] = qhat[(((size_t)bh) * NBLK + qi) * HD + tid];
    __syncthreads();
    const double* kr = &khat[(((size_t)bh) * NBLK + tid) * HD];
    double s = 0.0;
    for (int d = 0; d < 64; ++d) s += qr[d] * kr[d];
    s *= 0.125;
    red[tid] = s;
    __syncthreads();
    for (int off = 64; off > 0; off >>= 1) {
        if (tid < off) red[tid] = fmax(red[tid], red[tid + off]);
        __syncthreads();
    }
    double pen = (tcd[b * NBLK + qi] * tcd[b * NBLK + tid] < 0.5) ? 1e4 : 0.0;
    lrl[(size_t)bh * (NBLK*NBLK) + (size_t)qi * NBLK + tid] = s - pen;
    if (tid == 0) rmax[bh * NBLK + qi] = red[0];
}

// ---------------------------------------------------------------------------
// 5) v_hat (f32) + tc (f32)
// ---------------------------------------------------------------------------
__global__ __launch_bounds__(64) void vhat_kernel(
    const float* __restrict__ V, const float* __restrict__ am,
    float* __restrict__ vhat, float* __restrict__ tcf)
{
    int blk = blockIdx.x & 127, bh = blockIdx.x >> 7;
    int b = bh / 12;
    int d = threadIdx.x;
    const float* amb = am + b * S_LEN + blk * 32;
    float tc = 0.f;
    for (int t = 0; t < 32; ++t) tc += 1.0f + amb[t] * 1e-4f;
    float s = 0.f;
    size_t base = (((size_t)bh) * S_LEN + blk * 32) * HD + d;
    for (int t = 0; t < 32; ++t) s += V[base + (size_t)t * HD];
    vhat[(((size_t)bh) * NBLK + blk) * HD + d] = s / (tc + 1e-6f);
    if (d == 0) tcf[bh * NBLK + blk] = tc;
}

// ---------------------------------------------------------------------------
// 6) top-512 radix select + per-(bh,qi) lists.
// ---------------------------------------------------------------------------
__device__ __forceinline__ unsigned long long sel_key(const double* lp, const double* rm, int i)
{
    int qi = i >> 7, ki = i & 127;
    double s = lp[i] - rm[qi];
    int dd = qi - ki; if (dd < 0) dd = -dd;
    if (dd <= 1) s += 5000.0;
    unsigned long long u = (unsigned long long)__double_as_longlong(s);
    u = (u >> 63) ? ~u : (u | 0x8000000000000000ULL);
    return u;
}

__global__ __launch_bounds__(256) void topk_kernel(
    const double* __restrict__ lrl, const double* __restrict__ rmax,
    double* __restrict__ th64, int* __restrict__ cnt, unsigned char* __restrict__ lists,
    int* __restrict__ eqbuf, int* __restrict__ eqcnt)
{
    const int bh = blockIdx.x, tid = threadIdx.x;
    __shared__ int hist[256];
    __shared__ unsigned long long s_pref;
    __shared__ int s_K;
    const double* lp = lrl + (size_t)bh * (NBLK*NBLK);
    const double* rm = rmax + bh * NBLK;
    if (tid < 128) cnt[bh * NBLK + tid] = 0;
    if (tid == 0) eqcnt[bh] = 0;

    unsigned long long pref = 0, pmask = 0;
    int K = 512;
    for (int by = 7; by >= 0; --by) {
        hist[tid] = 0;
        __syncthreads();
        for (int i = tid; i < NBLK*NBLK; i += 256) {
            unsigned long long u = sel_key(lp, rm, i);
            if ((u & pmask) == pref)
                atomicAdd(&hist[(int)((u >> (by*8)) & 255)], 1);
        }
        __syncthreads();
        if (tid == 0) {
            int c = 0, bsel = 0;
            for (int x = 255; x >= 0; --x) {
                if (c + hist[x] >= K) { bsel = x; break; }
                c += hist[x];
            }
            s_pref = pref | ((unsigned long long)bsel << (by*8));
            s_K = K - c;
        }
        __syncthreads();
        pref = s_pref; K = s_K;
        pmask |= 0xFFULL << (by*8);
        __syncthreads();
    }
    const unsigned long long tkey = pref;
    int n_take = K;
    if (tid == 0) {
        unsigned long long u = (tkey & 0x8000000000000000ULL) ? (tkey ^ 0x8000000000000000ULL) : ~tkey;
        th64[bh] = __longlong_as_double((long long)u);
    }
    for (int i = tid; i < NBLK*NBLK; i += 256) {
        unsigned long long u = sel_key(lp, rm, i);
        if (u > tkey) {
            int qi = i >> 7, ki = i & 127;
            int pos = atomicAdd(&cnt[bh * NBLK + qi], 1);
            lists[(((size_t)bh) * NBLK + qi) * NBLK + pos] = (unsigned char)ki;
        } else if (u == tkey) {
            int e = atomicAdd(&eqcnt[bh], 1);
            if (e < 512) eqbuf[bh * 512 + e] = i;
        }
    }
    __syncthreads();
    if (tid == 0) {
        int ne = eqcnt[bh]; if (ne > 512) ne = 512;
        int* eb = &eqbuf[bh * 512];
        for (int a = 1; a < ne; ++a) {
            int v = eb[a]; int x = a - 1;
            while (x >= 0 && eb[x] > v) { eb[x+1] = eb[x]; --x; }
            eb[x+1] = v;
        }
        if (n_take > ne) n_take = ne;
        for (int j = 0; j < n_take; ++j) {
            int i = eb[j]; int qi = i >> 7, ki = i & 127;
            int pos = cnt[bh * NBLK + qi]++;
            lists[(((size_t)bh) * NBLK + qi) * NBLK + pos] = (unsigned char)ki;
        }
    }
    __syncthreads();
    if (tid < 128) {
        int n = cnt[bh * NBLK + tid];
        unsigned char* l = &lists[(((size_t)bh) * NBLK + tid) * NBLK];
        for (int a = 1; a < n; ++a) {
            unsigned char v = l[a]; int x = a - 1;
            while (x >= 0 && l[x] > v) { l[x+1] = l[x]; --x; }
            l[x+1] = v;
        }
    }
}

// ---------------------------------------------------------------------------
// 7) High-res sparse attention + low-res branch + combine.
// ---------------------------------------------------------------------------
__device__ __forceinline__ float dot64(const float (*kv)[68], int k, const float* qreg)
{
    float s = 0.f;
    #pragma unroll
    for (int x = 0; x < 16; ++x) {
        float4 kvv = *(const float4*)&kv[k][x*4];
        s += kvv.x * qreg[x*4+0];
        s += kvv.y * qreg[x*4+1];
        s += kvv.z * qreg[x*4+2];
        s += kvv.w * qreg[x*4+3];
    }
    return s;
}

__global__ __launch_bounds__(256) void hr_kernel(
    const float* __restrict__ Q, const float* __restrict__ Kf, const float* __restrict__ Vf,
    const double* __restrict__ lrl64, const double* __restrict__ rmax64, const double* __restrict__ th64,
    const int* __restrict__ cnt, const unsigned char* __restrict__ lists,
    const float* __restrict__ vhat, const float* __restrict__ tcf,
    const float* __restrict__ am, float* __restrict__ out)
{
    const int qi = blockIdx.x, bh = blockIdx.y;
    const int tid = threadIdx.x;
    __shared__ float qb[32][68];
    __shared__ float kv[32][68];
    __shared__ float vb[32][68];
    __shared__ float eL[32][33];
    __shared__ float red[8][33];
    __shared__ float mrow[32], nrm[32], wlr[128], lrvec[64];
    __shared__ float s_lrn;

    const int q  = tid & 31;
    const int g  = tid >> 5;
    const int d0 = g * 8;

    {
        int t = tid >> 3, dq = (tid & 7) * 8;
        const float* src = &Q[(((size_t)bh) * S_LEN + qi*32 + t) * HD + dq];
        float4 x0 = *(const float4*)src, x1 = *(const float4*)(src + 4);
        qb[t][dq+0]=x0.x; qb[t][dq+1]=x0.y; qb[t][dq+2]=x0.z; qb[t][dq+3]=x0.w;
        qb[t][dq+4]=x1.x; qb[t][dq+5]=x1.y; qb[t][dq+6]=x1.z; qb[t][dq+7]=x1.w;
    }
    if (tid < 32) mrow[tid] = -1e9f;
    const int c = cnt[bh * NBLK + qi];
    const unsigned char* ml = &lists[(((size_t)bh) * NBLK + qi) * NBLK];
    __syncthreads();

    float qreg[64];
    #pragma unroll
    for (int x = 0; x < 16; ++x) {
        float4 t4 = *(const float4*)&qb[q][x*4];
        qreg[x*4+0]=t4.x; qreg[x*4+1]=t4.y; qreg[x*4+2]=t4.z; qreg[x*4+3]=t4.w;
    }

    for (int bi = 0; bi < c; ++bi) {
        int ki = ml[bi];
        int t = tid >> 3, dq = (tid & 7) * 8;
        const float* ks = &Kf[(((size_t)bh) * S_LEN + ki*32 + t) * HD + dq];
        float4 k0 = *(const float4*)ks, k1 = *(const float4*)(ks + 4);
        __syncthreads();
        kv[t][dq+0]=k0.x; kv[t][dq+1]=k0.y; kv[t][dq+2]=k0.z; kv[t][dq+3]=k0.w;
        kv[t][dq+4]=k1.x; kv[t][dq+5]=k1.y; kv[t][dq+6]=k1.z; kv[t][dq+7]=k1.w;
        __syncthreads();
        float lm = -1e30f;
        #pragma unroll
        for (int j = 0; j < 4; ++j) {
            float s = dot64(kv, g*4 + j, qreg) * 0.125f;
            lm = fmaxf(lm, s);
        }
        red[g][q] = lm;
        __syncthreads();
        if (tid < 32) {
            float m = mrow[tid];
            #pragma unroll
            for (int x = 0; x < 8; ++x) m = fmaxf(m, red[x][tid]);
            mrow[tid] = m;
        }
    }
    __syncthreads();

    float acc[8] = {0,0,0,0,0,0,0,0};
    float nsum = 0.f;
    for (int bi = 0; bi < c; ++bi) {
        int ki = ml[bi];
        int t = tid >> 3, dq = (tid & 7) * 8;
        const float* ks = &Kf[(((size_t)bh) * S_LEN + ki*32 + t) * HD + dq];
        const float* vs = &Vf[(((size_t)bh) * S_LEN + ki*32 + t) * HD + dq];
        float4 k0 = *(const float4*)ks, k1 = *(const float4*)(ks + 4);
        float4 v0 = *(const float4*)vs, v1 = *(const float4*)(vs + 4);
        __syncthreads();
        kv[t][dq+0]=k0.x; kv[t][dq+1]=k0.y; kv[t][dq+2]=k0.z; kv[t][dq+3]=k0.w;
        kv[t][dq+4]=k1.x; kv[t][dq+5]=k1.y; kv[t][dq+6]=k1.z; kv[t][dq+7]=k1.w;
        vb[t][dq+0]=v0.x; vb[t][dq+1]=v0.y; vb[t][dq+2]=v0.z; vb[t][dq+3]=v0.w;
        vb[t][dq+4]=v1.x; vb[t][dq+5]=v1.y; vb[t][dq+6]=v1.z; vb[t][dq+7]=v1.w;
        __syncthreads();
        #pragma unroll
        for (int j = 0; j < 4; ++j) {
            int k = g*4 + j;
            float s = dot64(kv, k, qreg) * 0.125f;
            eL[k][q] = expf(s - mrow[q]);
        }
        __syncthreads();
        #pragma unroll 4
        for (int k = 0; k < 32; ++k) {
            float e = eL[k][q];
            if (g == 0) nsum += e;
            float4 w0 = *(const float4*)&vb[k][d0];
            float4 w1 = *(const float4*)&vb[k][d0+4];
            acc[0] += e*w0.x; acc[1] += e*w0.y; acc[2] += e*w0.z; acc[3] += e*w0.w;
            acc[4] += e*w1.x; acc[5] += e*w1.y; acc[6] += e*w1.z; acc[7] += e*w1.w;
        }
    }
    if (g == 0) nrm[q] = nsum;
    __syncthreads();

    const double thv  = th64[bh];
    const double rm64 = rmax64[bh * NBLK + qi];
    if (tid < 128) {
        int m = tid;
        double lv = lrl64[(size_t)bh * (NBLK*NBLK) + (size_t)qi * NBLK + m];
        int dd = qi - m; if (dd < 0) dd = -dd;
        double s = lv - rm64 + ((dd <= 1) ? 5000.0 : 0.0);
        float w;
        if (s >= thv) w = 0.f;
        else          w = (float)exp(lv - rm64) * tcf[bh * NBLK + m];
        wlr[m] = w;
    }
    __syncthreads();
    if (tid == 0) {
        float t = 0.f;
        for (int m = 0; m < 128; ++m) t += wlr[m];
        s_lrn = t;
    }
    if (tid < 64) {
        float a = 0.f;
        for (int m = 0; m < 128; ++m)
            a += wlr[m] * vhat[(((size_t)bh) * NBLK + m) * HD + tid];
        lrvec[tid] = a;
    }
    __syncthreads();

    const int b = bh / 12, h = bh % 12;
    const int srow = qi*32 + q;
    float mv  = 1.0f + am[b * S_LEN + srow] * 1e-4f;
    float mq  = mrow[q];
    float logc = ((float)rm64 - mq) * mv;
    float lrc = (logc <= 0.f) ? expf(logc)  : 1.0f;
    float hrc = (logc >  0.f) ? expf(-logc) : 1.0f;
    float den = nrm[q] * hrc + s_lrn * lrc + 1e-6f;
    float sc  = mv / den;
    size_t ob = ((size_t)(b * S_LEN + srow)) * 768 + h * HD + d0;
    #pragma unroll
    for (int j = 0; j < 8; ++j)
        out[ob + j] = (acc[j] * hrc + lrvec[d0 + j] * lrc) * sc;
}

// ---------------------------------------------------------------------------
extern "C" void kernel_launch(void* const* d_in, const int* in_sizes, int n_in,
                              void* d_out, int out_size, void* d_ws, size_t ws_size,
                              hipStream_t stream)
{
    (void)in_sizes; (void)n_in; (void)out_size; (void)ws_size;
    const float* X  = (const float*)d_in[0];
    const float* am = (const float*)d_in[1];
    const float* Wq = (const float*)d_in[2];
    const float* bq = (const float*)d_in[3];
    const float* Wk = (const float*)d_in[4];
    const float* bk = (const float*)d_in[5];
    const float* Wv = (const float*)d_in[6];
    const float* bv = (const float*)d_in[7];
    float* out = (float*)d_out;

    char* p = (char*)d_ws;
    // persistent across whole pipeline
    float* Qf   = (float*)p; p += (size_t)BHT * S_LEN * HD * 4;
    float* Kf   = (float*)p; p += (size_t)BHT * S_LEN * HD * 4;
    float* Vf   = (float*)p; p += (size_t)BHT * S_LEN * HD * 4;
    char* region = p;

    // ---- phase A layout (dead after qkv_mfma): bf16 splits ----
    char* pa = region;
    u16* Xh = (u16*)pa; pa += (size_t)16384 * 768 * 2;
    u16* Xl = (u16*)pa; pa += (size_t)16384 * 768 * 2;
    u16* Wh = (u16*)pa; pa += (size_t)3 * 768 * 768 * 2;
    u16* Wl = (u16*)pa; pa += (size_t)3 * 768 * 768 * 2;

    // ---- phase B/C layout (reuses phase A region) ----
    char* pb = region;
    double* hsum   = (double*)pb; pb += (size_t)512 * 768 * 8;
    double* tcd    = (double*)pb; pb += (size_t)512 * 8;
    double* qhat64 = (double*)pb; pb += (size_t)BHT * NBLK * HD * 8;
    double* khat64 = (double*)pb; pb += (size_t)BHT * NBLK * HD * 8;
    double* lrl64  = (double*)pb; pb += (size_t)BHT * NBLK * NBLK * 8;
    double* rmax64 = (double*)pb; pb += (size_t)BHT * NBLK * 8;
    double* th64   = (double*)pb; pb += (size_t)BHT * 8;
    float* vhat = (float*)pb; pb += (size_t)BHT * NBLK * HD * 4;
    float* tcf  = (float*)pb; pb += (size_t)BHT * NBLK * 4;
    int* cnt    = (int*)pb;   pb += (size_t)BHT * NBLK * 4;
    int* eqbuf  = (int*)pb;   pb += (size_t)BHT * 512 * 4;
    int* eqcnt  = (int*)pb;   pb += (size_t)BHT * 4;
    unsigned char* lists = (unsigned char*)pb; pb += (size_t)BHT * NBLK * NBLK;

    // phase A: splits + MFMA QKV projection
    split_kernel<<<6144, 256, 0, stream>>>(X, Xh, Xl, 16384 * 768 / 8);
    split_kernel<<<288, 256, 0, stream>>>(Wq, Wh + 0*768*768, Wl + 0*768*768, 768 * 768 / 8);
    split_kernel<<<288, 256, 0, stream>>>(Wk, Wh + 1*768*768, Wl + 1*768*768, 768 * 768 / 8);
    split_kernel<<<288, 256, 0, stream>>>(Wv, Wh + 2*768*768, Wl + 2*768*768, 768 * 768 / 8);
    qkv_mfma<<<dim3(6, 128, 3), 256, 0, stream>>>(Xh, Xl, Wh, Wl, bq, bk, bv, am, Qf, Kf, Vf);

    // phase B: f64 selection path (region reused — stream order serializes)
    hsum_kernel<<<512, 256, 0, stream>>>(X, am, hsum, tcd);
    ghat_kernel<<<dim3(12, 8, 2), 256, 0, stream>>>(hsum, Wq, Wk, bq, bk, tcd, qhat64, khat64);
    lrl_kernel<<<dim3(128, BHT), 128, 0, stream>>>(qhat64, khat64, tcd, lrl64, rmax64);
    vhat_kernel<<<BHT * NBLK, 64, 0, stream>>>(Vf, am, vhat, tcf);
    topk_kernel<<<BHT, 256, 0, stream>>>(lrl64, rmax64, th64, cnt, lists, eqbuf, eqcnt);

    // phase C
    hr_kernel<<<dim3(NBLK, BHT), 256, 0, stream>>>(Qf, Kf, Vf, lrl64, rmax64, th64,
                                                   cnt, lists, vhat, tcf, am, out);
}